// Round 1
// 899.109 us; speedup vs baseline: 1.1369x; 1.1369x over previous
//
#include <hip/hip_runtime.h>
#include <cstdint>
#include <cstddef>

// ---------------------------------------------------------------------------
// DHSNN: T=250, N=256, IN=1024, H=1024, OUT=35, B=4, IN_B=256
// R5: gemm1 restructured — double-buffered LDS pipeline (1 raw barrier per
// K-step, counted-free prefetch instead of 2x full vmcnt(0) drains), chunk-XOR
// LDS swizzle (kills the 8-way ds_read_b128 bank conflict), XCD-chunked block
// swizzle (A-panel L2 reuse). scan/gemm2/out unchanged from R4.
// ---------------------------------------------------------------------------

typedef __bf16 bf16;
typedef __bf16 bf16x8 __attribute__((ext_vector_type(8)));
typedef float  f32x4  __attribute__((ext_vector_type(4)));

#define Tt    250
#define Nn    256
#define Hh    1024
#define OUTK  35
#define NBR   4

// ws layout (fixed offsets, all 256-aligned)
#define OFF_FLAG 0u
#define OFF_WBT  256u                // 4*1024*256*2      = 2,097,152
#define OFF_W2T  2097408u            // 48*1024*2         =    98,304
#define OFF_ALF  2195712u            // 4096*4
#define OFF_OMF  2212096u
#define OFF_BBF  2228480u
#define OFF_B2S  2244864u            // 48 b2f + [48]=tau1 + [49]=tau2
#define OFF_H2   2245120u            // 256*250*48*4      = 12,288,000
#define OFF_STW  14533120u           // 4*256*1024*4      =  4,194,304
#define OFF_V1W  18727424u           // 256*1024*4        =  1,048,576
#define OFF_S1P  19776000u           // 250*256*16*8      =  8,192,000
#define OFF_BIN  27968000u           // TC*4*256*1024*2   = TC*2,097,152 (bf16)
#define FIXED_WS 27968000u

__device__ __forceinline__ float ld_in(const void* p, size_t i, int f32) {
    return f32 ? ((const float*)p)[i] : (float)((const bf16*)p)[i];
}

__device__ __forceinline__ void gload16(const void* g, void* l) {
    __builtin_amdgcn_global_load_lds(
        (const __attribute__((address_space(1))) void*)g,
        (__attribute__((address_space(3))) void*)l, 16, 0, 0);
}

// ------------------------------ dtype sniff --------------------------------
__global__ void sniff_kernel(const unsigned short* __restrict__ x,
                             int* __restrict__ flag) {
    int cnt = 0;
    for (int i = threadIdx.x; i < 4096; i += 64) {
        int e = (x[i] >> 7) & 0xFF;
        cnt += (e >= 100 && e <= 140) ? 1 : 0;
    }
#pragma unroll
    for (int o = 32; o > 0; o >>= 1) cnt += __shfl_xor(cnt, o);
    if (threadIdx.x == 0) *flag = (cnt < 3400) ? 1 : 0;   // 1 = fp32 inputs
}

// --------------------------- transpose Wb ----------------------------------
__global__ void trans_wb_kernel(const void* __restrict__ Wb, bf16* __restrict__ WbT,
                                const int* __restrict__ flagp) {
    int f32 = *flagp;
    __shared__ bf16 tile[32][33];
    int bid = blockIdx.x;              // 1024 = 4 * 8 * 32
    int b   = bid >> 8;
    int rem = bid & 255;
    int kt  = rem >> 5;
    int htl = rem & 31;
    int tx = threadIdx.x & 31, ty = threadIdx.x >> 5;
#pragma unroll
    for (int i = 0; i < 4; ++i) {
        int k = kt * 32 + ty + i * 8;
        int h = htl * 32 + tx;
        tile[ty + i * 8][tx] = (bf16)ld_in(Wb, (size_t)(b * 256 + k) * 1024 + h, f32);
    }
    __syncthreads();
#pragma unroll
    for (int i = 0; i < 4; ++i) {
        int h = htl * 32 + ty + i * 8;
        int k = kt * 32 + tx;
        WbT[((size_t)b * 1024 + h) * 256 + k] = tile[tx][ty + i * 8];
    }
}

// --------------------------- transpose W2 ----------------------------------
__global__ void trans_w2_kernel(const void* __restrict__ W2, bf16* __restrict__ W2T,
                                const int* __restrict__ flagp) {
    int f32 = *flagp;
    int idx = blockIdx.x * 256 + threadIdx.x;   // 48*1024
    int c = idx >> 10;
    int k = idx & 1023;
    W2T[idx] = (c < OUTK) ? (bf16)ld_in(W2, (size_t)k * OUTK + c, f32) : (bf16)0.0f;
}

// ------------------------------ prep small ---------------------------------
__global__ void prep_kernel(const void* taus, const void* bb, const void* b2,
                            const void* tau1, const void* tau2,
                            float* alf, float* omf, float* bbf, float* b2s,
                            const int* __restrict__ flagp) {
    int f32 = *flagp;
    int idx = blockIdx.x * 256 + threadIdx.x;
    if (idx < 4096) {
        float tv = ld_in(taus, idx, f32);
        float a = 1.0f / (1.0f + expf(-tv));
        alf[idx] = a;
        omf[idx] = 1.0f - a;
        bbf[idx] = ld_in(bb, idx, f32);
    } else if (idx < 4144) {
        int c = idx - 4096;
        b2s[c] = (c < OUTK) ? ld_in(b2, c, f32) : 0.0f;
    } else if (idx == 4144) {
        b2s[48] = ld_in(tau1, 0, f32);
    } else if (idx == 4145) {
        b2s[49] = ld_in(tau2, 0, f32);
    }
}

// --------------------------- GEMM1: x @ Wb ---------------------------------
// bin[b][m][h] (bf16) = sum_k x[m][b*256+k] * WbT[b][h][k]; m = t*256+n
// grid = 4 * (TCl*2) * 8; tile 128x128, BK=32, K=256.
// Double-buffered: stage kc+1 (B: global_load_lds, A: regs) while MFMA on kc.
// LDS chunk-XOR swizzle slot = q ^ ((row>>1)&3) on A-write / B-global-source /
// both reads (rule: both-sides-or-neither with global_load_lds).
__global__ __launch_bounds__(256, 2)
void gemm1_kernel(const void* __restrict__ xsrc,
                  const bf16* __restrict__ BT, bf16* __restrict__ C,
                  const int* __restrict__ flagp, int TCl) {
    __shared__ bf16 Alds[2][4096];
    __shared__ bf16 Blds[2][4096];
    int f32 = *flagp;
    int tid = threadIdx.x;
    int tiles_pb = TCl * 16;

    // XCD-chunked swizzle: consecutive tiles (sharing the A m-panel) land on
    // the same XCD's L2. grid = 64*TCl is %8==0 for all TC candidates.
    int nwg = gridDim.x;
    int bid = blockIdx.x;
    int tile = ((nwg & 7) == 0) ? ((bid & 7) * (nwg >> 3) + (bid >> 3)) : bid;

    int branch = tile / tiles_pb;
    int rem = tile % tiles_pb;
    int mt = rem >> 3, ht = rem & 7;
    int w = tid >> 6, lane = tid & 63;
    int l15 = lane & 15, l4 = lane >> 4;
    int wm = w >> 1, wh = w & 1;
    const int m0 = mt * 128, h0 = ht * 128;

    const int row = tid >> 2;          // 0..63 (row within 64-row half)
    const int q   = tid & 3;           // 16B chunk within the 64B row-slice
    const int swr = (tid >> 3) & 3;    // (row>>1)&3 — swizzle key, write side
    const int srd = (l15 >> 1) & 3;    // swizzle key, read side

    f32x4 zero = {0.f, 0.f, 0.f, 0.f};
    f32x4 acc[4][4];
#pragma unroll
    for (int mi = 0; mi < 4; ++mi)
#pragma unroll
        for (int hi = 0; hi < 4; ++hi) acc[mi][hi] = zero;

    const bf16* Bbase = BT + (size_t)branch * (1024 * 256) + (size_t)h0 * 256;

    float4 anxt[2][2];   // fp32-input staging regs
    bf16x8 bnxt[2];      // bf16-input staging regs

    auto issueB = [&](int kc, int pp) {
#pragma unroll
        for (int r = 0; r < 2; ++r)
            gload16(Bbase + (size_t)(r * 64 + row) * 256 + kc * 32 + (q ^ swr) * 8,
                    &Blds[pp][(size_t)(r * 256 + tid) * 8]);
    };
    auto issueA = [&](int kc) {
        if (f32) {
#pragma unroll
            for (int r = 0; r < 2; ++r) {
                const float4* pa = (const float4*)((const float*)xsrc +
                    ((size_t)(m0 + r * 64 + row) * 1024 + branch * 256 + kc * 32 + q * 8));
                anxt[r][0] = pa[0];
                anxt[r][1] = pa[1];
            }
        } else {
#pragma unroll
            for (int r = 0; r < 2; ++r)
                bnxt[r] = *(const bf16x8*)((const bf16*)xsrc +
                    ((size_t)(m0 + r * 64 + row) * 1024 + branch * 256 + kc * 32 + q * 8));
        }
    };
    auto writeA = [&](int pp) {
#pragma unroll
        for (int r = 0; r < 2; ++r) {
            bf16x8 av;
            if (f32) {
                float4 u0 = anxt[r][0], u1 = anxt[r][1];
                av[0] = (bf16)u0.x; av[1] = (bf16)u0.y;
                av[2] = (bf16)u0.z; av[3] = (bf16)u0.w;
                av[4] = (bf16)u1.x; av[5] = (bf16)u1.y;
                av[6] = (bf16)u1.z; av[7] = (bf16)u1.w;
            } else {
                av = bnxt[r];
            }
            *(bf16x8*)&Alds[pp][(size_t)(r * 64 + row) * 32 + (q ^ swr) * 8] = av;
        }
    };

    // ---- prologue: stage kc=0 into buffer 0 ----
    issueB(0, 0);
    issueA(0);
    asm volatile("s_waitcnt vmcnt(0)" ::: "memory");
    writeA(0);
    asm volatile("s_waitcnt lgkmcnt(0)" ::: "memory");
    __builtin_amdgcn_s_barrier();

#pragma unroll
    for (int kc = 0; kc < 8; ++kc) {
        const int p = kc & 1;
        if (kc < 7) {
            issueB(kc + 1, p ^ 1);   // prefetch B(kc+1), stays in flight across MFMA
            issueA(kc + 1);          // prefetch A(kc+1) into regs
        }
        __builtin_amdgcn_sched_barrier(0);   // pin prefetch issue above compute
        bf16x8 af[4], bfr[4];
#pragma unroll
        for (int mi = 0; mi < 4; ++mi)
            af[mi] = *(const bf16x8*)&Alds[p][(wm * 64 + mi * 16 + l15) * 32 + (l4 ^ srd) * 8];
#pragma unroll
        for (int hi = 0; hi < 4; ++hi)
            bfr[hi] = *(const bf16x8*)&Blds[p][(wh * 64 + hi * 16 + l15) * 32 + (l4 ^ srd) * 8];
#pragma unroll
        for (int mi = 0; mi < 4; ++mi)
#pragma unroll
            for (int hi = 0; hi < 4; ++hi)
                acc[mi][hi] = __builtin_amdgcn_mfma_f32_16x16x32_bf16(
                    af[mi], bfr[hi], acc[mi][hi], 0, 0, 0);
        if (kc < 7) {
            asm volatile("s_waitcnt vmcnt(0)" ::: "memory");   // B(kc+1) in LDS, anxt arrived
            writeA(p ^ 1);
            asm volatile("s_waitcnt lgkmcnt(0)" ::: "memory"); // drains frag reads + A writes
        } else {
            asm volatile("s_waitcnt lgkmcnt(0)" ::: "memory"); // drain frag reads pre-barrier
        }
        __builtin_amdgcn_s_barrier();
    }

    bf16* Cb = C + (size_t)branch * ((size_t)TCl * 256 * 1024);
#pragma unroll
    for (int mi = 0; mi < 4; ++mi)
#pragma unroll
        for (int hi = 0; hi < 4; ++hi) {
            int rr = m0 + wm * 64 + mi * 16 + l4 * 4;
            int col = h0 + wh * 64 + hi * 16 + l15;
#pragma unroll
            for (int r = 0; r < 4; ++r)
                Cb[(size_t)(rr + r) * 1024 + col] = (bf16)acc[mi][hi][r];
        }
}

// --------------------- P2: dendritic scan + LIF1 (bit-pack s1) -------------
// one thread per (n,h); TCC=0 -> runtime trip count (no prefetch pipelining)
template<int TCC>
__global__ void scan_kernel(const bf16* __restrict__ bin,
                            const float* __restrict__ alf,
                            const float* __restrict__ omf,
                            const float* __restrict__ bbf,
                            const float* __restrict__ b2s,
                            unsigned long long* __restrict__ s1p,
                            float* __restrict__ stw,
                            float* __restrict__ v1w,
                            int t0, int TCl_rt) {
    const int TCl = TCC ? TCC : TCl_rt;
    int n = blockIdx.x >> 2;
    int h = (blockIdx.x & 3) * 256 + threadIdx.x;
    int lane = threadIdx.x & 63;
    int widx = (blockIdx.x & 3) * 4 + (threadIdx.x >> 6);
    size_t CHEc = (size_t)TCl * 256 * 1024;
    size_t base = (size_t)n * 1024 + h;

    float al[NBR], om[NBR], bbv[NBR], st[NBR];
    float v1;
#pragma unroll
    for (int b = 0; b < NBR; ++b) {
        al[b] = alf[b * Hh + h];
        om[b] = omf[b * Hh + h];
        bbv[b] = bbf[b * Hh + h];
    }
    if (t0 == 0) {
#pragma unroll
        for (int b = 0; b < NBR; ++b) st[b] = 0.f;
        v1 = 0.f;
    } else {
#pragma unroll
        for (int b = 0; b < NBR; ++b)
            st[b] = stw[((size_t)b * Nn + n) * Hh + h];
        v1 = v1w[(size_t)n * Hh + h];
    }
    float tau1 = b2s[48];

    float nxt[NBR];
#pragma unroll
    for (int b = 0; b < NBR; ++b) nxt[b] = (float)bin[b * CHEc + base];

#pragma unroll 2
    for (int tl = 0; tl < TCl; ++tl) {
        float cur[NBR];
#pragma unroll
        for (int b = 0; b < NBR; ++b) cur[b] = nxt[b];
        if (tl + 1 < TCl) {
            size_t nb = base + (size_t)(tl + 1) * (256 * 1024);
#pragma unroll
            for (int b = 0; b < NBR; ++b) nxt[b] = (float)bin[b * CHEc + nb];
        }
#pragma unroll
        for (int b = 0; b < NBR; ++b)
            st[b] = al[b] * st[b] + om[b] * (cur[b] + bbv[b]);
        float comb = st[0] + st[1] + st[2] + st[3];
        v1 += (comb - v1) / tau1;
        bool sp = (v1 >= 1.0f);
        unsigned long long m = __ballot(sp);
        if (lane == 0)
            s1p[((size_t)(t0 + tl) * Nn + n) * 16 + widx] = m;
        if (sp) v1 = 0.f;
    }
#pragma unroll
    for (int b = 0; b < NBR; ++b) stw[((size_t)b * Nn + n) * Hh + h] = st[b];
    v1w[(size_t)n * Hh + h] = v1;
}

// --------------------------- GEMM2: s1 @ W2 --------------------------------
__global__ __launch_bounds__(256, 2)
void gemm2_kernel(const unsigned char* __restrict__ s1b,
                  const bf16* __restrict__ W2T, float* __restrict__ h2) {
    __shared__ bf16 Alds[4096];
    __shared__ bf16 Blds[1536];
    int tid = threadIdx.x;
    int m0 = blockIdx.x * 128;
    int w = tid >> 6, lane = tid & 63;
    int l15 = lane & 15, l4 = lane >> 4;

    f32x4 zero = {0.f, 0.f, 0.f, 0.f};
    f32x4 acc[2][3];
#pragma unroll
    for (int mi = 0; mi < 2; ++mi)
#pragma unroll
        for (int hi = 0; hi < 3; ++hi) acc[mi][hi] = zero;

    const bf16 ONE = (bf16)1.0f, ZER = (bf16)0.0f;

    for (int kc = 0; kc < 32; ++kc) {
        bf16x8 av[2], bv;
#pragma unroll
        for (int r = 0; r < 2; ++r) {
            int L = r * 256 + tid;
            int row = L >> 2;
            unsigned char bits = s1b[(size_t)(m0 + row) * 128 + kc * 4 + (L & 3)];
#pragma unroll
            for (int j = 0; j < 8; ++j)
                av[r][j] = ((bits >> j) & 1) ? ONE : ZER;
        }
        if (tid < 192)
            bv = *(const bf16x8*)&W2T[(size_t)(tid >> 2) * 1024 + kc * 32 + (tid & 3) * 8];
        __syncthreads();
#pragma unroll
        for (int r = 0; r < 2; ++r)
            *(bf16x8*)&Alds[(size_t)(r * 256 + tid) * 8] = av[r];
        if (tid < 192)
            *(bf16x8*)&Blds[(size_t)tid * 8] = bv;
        __syncthreads();
        bf16x8 af[2], bfr[3];
#pragma unroll
        for (int mi = 0; mi < 2; ++mi)
            af[mi] = *(const bf16x8*)&Alds[(w * 32 + mi * 16 + l15) * 32 + l4 * 8];
#pragma unroll
        for (int hi = 0; hi < 3; ++hi)
            bfr[hi] = *(const bf16x8*)&Blds[(hi * 16 + l15) * 32 + l4 * 8];
#pragma unroll
        for (int mi = 0; mi < 2; ++mi)
#pragma unroll
            for (int hi = 0; hi < 3; ++hi)
                acc[mi][hi] = __builtin_amdgcn_mfma_f32_16x16x32_bf16(
                    af[mi], bfr[hi], acc[mi][hi], 0, 0, 0);
        __syncthreads();
    }
#pragma unroll
    for (int mi = 0; mi < 2; ++mi)
#pragma unroll
        for (int hi = 0; hi < 3; ++hi) {
            int col = hi * 16 + l15;
#pragma unroll
            for (int r = 0; r < 4; ++r) {
                int m = m0 + w * 32 + mi * 16 + l4 * 4 + r;
                int t = m >> 8;
                int n = m & 255;
                h2[((size_t)n * Tt + t) * 48 + col] = acc[mi][hi][r];
            }
        }
}

// ------------------- P4: LIF2 scan + count + log_softmax (fp32 out) --------
__global__ void out_kernel(const float* __restrict__ h2,
                           const float* __restrict__ b2s,
                           float* __restrict__ out) {
    int n = blockIdx.x;
    int k = threadIdx.x;
    float b2v = (k < 48) ? b2s[k] : 0.f;
    float tau2 = b2s[49];
    float v2 = 0.f, acc = 0.f;
    const float* base = h2 + (size_t)n * Tt * 48;
    for (int t = 0; t < Tt; ++t) {
        float hv = (k < 48) ? base[t * 48 + k] : 0.f;
        hv += b2v;
        v2 += (hv - v2) / tau2;
        bool sp = (v2 >= 1.0f);
        if (sp) { acc += 1.f; v2 = 0.f; }
    }
    float val = (k < OUTK) ? acc : -3.0e38f;
    float mx = val;
#pragma unroll
    for (int o = 32; o > 0; o >>= 1) mx = fmaxf(mx, __shfl_xor(mx, o));
    float e = (k < OUTK) ? expf(val - mx) : 0.f;
    float s = e;
#pragma unroll
    for (int o = 32; o > 0; o >>= 1) s += __shfl_xor(s, o);
    if (k < OUTK) out[n * OUTK + k] = (val - mx) - logf(s);
}

// ---------------------------------------------------------------------------
extern "C" void kernel_launch(void* const* d_in, const int* in_sizes, int n_in,
                              void* d_out, int out_size, void* d_ws, size_t ws_size,
                              hipStream_t stream) {
    const void* x    = d_in[0];
    const void* Wb   = d_in[1];
    const void* bb   = d_in[2];
    const void* taus = d_in[3];
    const void* W2   = d_in[4];
    const void* b2   = d_in[5];
    const void* tau1 = d_in[6];
    const void* tau2 = d_in[7];
    float* out = (float*)d_out;

    char* ws = (char*)d_ws;
    int*   flag = (int*)(ws + OFF_FLAG);
    bf16*  WbT  = (bf16*)(ws + OFF_WBT);
    bf16*  W2T  = (bf16*)(ws + OFF_W2T);
    float* alf  = (float*)(ws + OFF_ALF);
    float* omf  = (float*)(ws + OFF_OMF);
    float* bbf  = (float*)(ws + OFF_BBF);
    float* b2s  = (float*)(ws + OFF_B2S);
    float* h2   = (float*)(ws + OFF_H2);
    float* stw  = (float*)(ws + OFF_STW);
    float* v1w  = (float*)(ws + OFF_V1W);
    unsigned long long* s1p = (unsigned long long*)(ws + OFF_S1P);
    bf16*  bin  = (bf16*)(ws + OFF_BIN);

    // largest t-chunk that fits (bin is bf16: TC * 2,097,152 bytes)
    const int cands[8] = {250, 125, 50, 25, 10, 5, 2, 1};
    int TC = 1;
    for (int i = 0; i < 8; ++i) {
        size_t need = (size_t)FIXED_WS + (size_t)cands[i] * 2097152u;
        if (need <= ws_size) { TC = cands[i]; break; }
    }

    sniff_kernel<<<1, 64, 0, stream>>>((const unsigned short*)x, flag);
    trans_wb_kernel<<<1024, 256, 0, stream>>>(Wb, WbT, flag);
    trans_w2_kernel<<<192, 256, 0, stream>>>(W2, W2T, flag);
    prep_kernel<<<17, 256, 0, stream>>>(taus, bb, b2, tau1, tau2,
                                        alf, omf, bbf, b2s, flag);

    int nch = Tt / TC;
    for (int c = 0; c < nch; ++c) {
        const void* xc = (const void*)((const char*)x +
            (size_t)c * TC * 256 * 1024 * 4);   // fp32 chunk offset (bf16 path
                                                // only triggers when TC==250)
        gemm1_kernel<<<64 * TC, 256, 0, stream>>>(xc, WbT, bin, flag, TC);
        if (TC == 250)
            scan_kernel<250><<<1024, 256, 0, stream>>>(
                bin, alf, omf, bbf, b2s, s1p, stw, v1w, c * TC, TC);
        else
            scan_kernel<0><<<1024, 256, 0, stream>>>(
                bin, alf, omf, bbf, b2s, s1p, stw, v1w, c * TC, TC);
    }
    gemm2_kernel<<<500, 256, 0, stream>>>((const unsigned char*)s1p, W2T, h2);
    out_kernel<<<Nn, 64, 0, stream>>>(h2, b2s, out);

    (void)in_sizes; (void)n_in; (void)out_size;
}

// Round 2
// 894.885 us; speedup vs baseline: 1.1423x; 1.0047x over previous
//
#include <hip/hip_runtime.h>
#include <cstdint>
#include <cstddef>

// ---------------------------------------------------------------------------
// DHSNN: T=250, N=256, IN=1024, H=1024, OUT=35, B=4, IN_B=256
// R6: gemm1 3-stage software pipeline with COUNTED vmcnt (T4): loads for
// K-step kc+2 issued at top of step kc, s_waitcnt vmcnt(4) after MFMA keeps
// next-next-step loads in flight across the barrier (never drain to 0 in
// steady state). 3 LDS buffers (48 KB), 2-deep A-register staging.
// Chunk-XOR LDS swizzle + XCD-chunked block swizzle kept from R5.
// scan/gemm2/out unchanged.
// ---------------------------------------------------------------------------

typedef __bf16 bf16;
typedef __bf16 bf16x8 __attribute__((ext_vector_type(8)));
typedef float  f32x4  __attribute__((ext_vector_type(4)));

#define Tt    250
#define Nn    256
#define Hh    1024
#define OUTK  35
#define NBR   4

// ws layout (fixed offsets, all 256-aligned)
#define OFF_FLAG 0u
#define OFF_WBT  256u                // 4*1024*256*2      = 2,097,152
#define OFF_W2T  2097408u            // 48*1024*2         =    98,304
#define OFF_ALF  2195712u            // 4096*4
#define OFF_OMF  2212096u
#define OFF_BBF  2228480u
#define OFF_B2S  2244864u            // 48 b2f + [48]=tau1 + [49]=tau2
#define OFF_H2   2245120u            // 256*250*48*4      = 12,288,000
#define OFF_STW  14533120u           // 4*256*1024*4      =  4,194,304
#define OFF_V1W  18727424u           // 256*1024*4        =  1,048,576
#define OFF_S1P  19776000u           // 250*256*16*8      =  8,192,000
#define OFF_BIN  27968000u           // TC*4*256*1024*2   = TC*2,097,152 (bf16)
#define FIXED_WS 27968000u

__device__ __forceinline__ float ld_in(const void* p, size_t i, int f32) {
    return f32 ? ((const float*)p)[i] : (float)((const bf16*)p)[i];
}

__device__ __forceinline__ void gload16(const void* g, void* l) {
    __builtin_amdgcn_global_load_lds(
        (const __attribute__((address_space(1))) void*)g,
        (__attribute__((address_space(3))) void*)l, 16, 0, 0);
}

// ------------------------------ dtype sniff --------------------------------
__global__ void sniff_kernel(const unsigned short* __restrict__ x,
                             int* __restrict__ flag) {
    int cnt = 0;
    for (int i = threadIdx.x; i < 4096; i += 64) {
        int e = (x[i] >> 7) & 0xFF;
        cnt += (e >= 100 && e <= 140) ? 1 : 0;
    }
#pragma unroll
    for (int o = 32; o > 0; o >>= 1) cnt += __shfl_xor(cnt, o);
    if (threadIdx.x == 0) *flag = (cnt < 3400) ? 1 : 0;   // 1 = fp32 inputs
}

// --------------------------- transpose Wb ----------------------------------
__global__ void trans_wb_kernel(const void* __restrict__ Wb, bf16* __restrict__ WbT,
                                const int* __restrict__ flagp) {
    int f32 = *flagp;
    __shared__ bf16 tile[32][33];
    int bid = blockIdx.x;              // 1024 = 4 * 8 * 32
    int b   = bid >> 8;
    int rem = bid & 255;
    int kt  = rem >> 5;
    int htl = rem & 31;
    int tx = threadIdx.x & 31, ty = threadIdx.x >> 5;
#pragma unroll
    for (int i = 0; i < 4; ++i) {
        int k = kt * 32 + ty + i * 8;
        int h = htl * 32 + tx;
        tile[ty + i * 8][tx] = (bf16)ld_in(Wb, (size_t)(b * 256 + k) * 1024 + h, f32);
    }
    __syncthreads();
#pragma unroll
    for (int i = 0; i < 4; ++i) {
        int h = htl * 32 + ty + i * 8;
        int k = kt * 32 + tx;
        WbT[((size_t)b * 1024 + h) * 256 + k] = tile[tx][ty + i * 8];
    }
}

// --------------------------- transpose W2 ----------------------------------
__global__ void trans_w2_kernel(const void* __restrict__ W2, bf16* __restrict__ W2T,
                                const int* __restrict__ flagp) {
    int f32 = *flagp;
    int idx = blockIdx.x * 256 + threadIdx.x;   // 48*1024
    int c = idx >> 10;
    int k = idx & 1023;
    W2T[idx] = (c < OUTK) ? (bf16)ld_in(W2, (size_t)k * OUTK + c, f32) : (bf16)0.0f;
}

// ------------------------------ prep small ---------------------------------
__global__ void prep_kernel(const void* taus, const void* bb, const void* b2,
                            const void* tau1, const void* tau2,
                            float* alf, float* omf, float* bbf, float* b2s,
                            const int* __restrict__ flagp) {
    int f32 = *flagp;
    int idx = blockIdx.x * 256 + threadIdx.x;
    if (idx < 4096) {
        float tv = ld_in(taus, idx, f32);
        float a = 1.0f / (1.0f + expf(-tv));
        alf[idx] = a;
        omf[idx] = 1.0f - a;
        bbf[idx] = ld_in(bb, idx, f32);
    } else if (idx < 4144) {
        int c = idx - 4096;
        b2s[c] = (c < OUTK) ? ld_in(b2, c, f32) : 0.0f;
    } else if (idx == 4144) {
        b2s[48] = ld_in(tau1, 0, f32);
    } else if (idx == 4145) {
        b2s[49] = ld_in(tau2, 0, f32);
    }
}

// --------------------------- GEMM1: x @ Wb ---------------------------------
// bin[b][m][h] (bf16) = sum_k x[m][b*256+k] * WbT[b][h][k]; m = t*256+n
// grid = 4 * (TCl*2) * 8; tile 128x128, BK=32, K=256 (8 K-steps).
// 3-stage pipeline: step kc issues loads for kc+2 (buf (kc+2)%3), computes
// buf kc%3, then waits vmcnt(4) (= step kc+1's loads done, kc+2's in
// flight), writes A(kc+1) to LDS, lgkmcnt(0)+s_barrier (single asm block so
// next-iter ds_reads cannot slip between wait and barrier).
// vmcnt(4) is safe for both dtype paths: f32 issues 6 loads/step (over-
// drains by 2), bf16 issues 4 (exact).
__global__ __launch_bounds__(256, 2)
void gemm1_kernel(const void* __restrict__ xsrc,
                  const bf16* __restrict__ BT, bf16* __restrict__ C,
                  const int* __restrict__ flagp, int TCl) {
    __shared__ bf16 Alds[3][4096];
    __shared__ bf16 Blds[3][4096];
    int f32 = *flagp;
    int tid = threadIdx.x;
    int tiles_pb = TCl * 16;

    // XCD-chunked swizzle: consecutive tiles (sharing the A m-panel) land on
    // the same XCD's L2. grid = 64*TCl is %8==0 for all TC candidates.
    int nwg = gridDim.x;
    int bid = blockIdx.x;
    int tile = ((nwg & 7) == 0) ? ((bid & 7) * (nwg >> 3) + (bid >> 3)) : bid;

    int branch = tile / tiles_pb;
    int rem = tile % tiles_pb;
    int mt = rem >> 3, ht = rem & 7;
    int w = tid >> 6, lane = tid & 63;
    int l15 = lane & 15, l4 = lane >> 4;
    int wm = w >> 1, wh = w & 1;
    const int m0 = mt * 128, h0 = ht * 128;

    const int row = tid >> 2;          // 0..63 (row within 64-row half)
    const int q   = tid & 3;           // 16B chunk within the 64B row-slice
    const int swr = (tid >> 3) & 3;    // (row>>1)&3 — swizzle key, write side
    const int srd = (l15 >> 1) & 3;    // swizzle key, read side

    f32x4 zero = {0.f, 0.f, 0.f, 0.f};
    f32x4 acc[4][4];
#pragma unroll
    for (int mi = 0; mi < 4; ++mi)
#pragma unroll
        for (int hi = 0; hi < 4; ++hi) acc[mi][hi] = zero;

    const bf16* Bbase = BT + (size_t)branch * (1024 * 256) + (size_t)h0 * 256;

    float4 anxt[2][2][2];   // [slot][r][half] fp32-input staging regs
    bf16x8 bnxt[2][2];      // [slot][r]       bf16-input staging regs

    auto issueB = [&](int kc, int pp) {
#pragma unroll
        for (int r = 0; r < 2; ++r)
            gload16(Bbase + (size_t)(r * 64 + row) * 256 + kc * 32 + (q ^ swr) * 8,
                    &Blds[pp][(size_t)(r * 256 + tid) * 8]);
    };
    auto issueA = [&](int kc, int sl) {
        if (f32) {
#pragma unroll
            for (int r = 0; r < 2; ++r) {
                const float4* pa = (const float4*)((const float*)xsrc +
                    ((size_t)(m0 + r * 64 + row) * 1024 + branch * 256 + kc * 32 + q * 8));
                anxt[sl][r][0] = pa[0];
                anxt[sl][r][1] = pa[1];
            }
        } else {
#pragma unroll
            for (int r = 0; r < 2; ++r)
                bnxt[sl][r] = *(const bf16x8*)((const bf16*)xsrc +
                    ((size_t)(m0 + r * 64 + row) * 1024 + branch * 256 + kc * 32 + q * 8));
        }
    };
    auto writeA = [&](int pp, int sl) {
#pragma unroll
        for (int r = 0; r < 2; ++r) {
            bf16x8 av;
            if (f32) {
                float4 u0 = anxt[sl][r][0], u1 = anxt[sl][r][1];
                av[0] = (bf16)u0.x; av[1] = (bf16)u0.y;
                av[2] = (bf16)u0.z; av[3] = (bf16)u0.w;
                av[4] = (bf16)u1.x; av[5] = (bf16)u1.y;
                av[6] = (bf16)u1.z; av[7] = (bf16)u1.w;
            } else {
                av = bnxt[sl][r];
            }
            *(bf16x8*)&Alds[pp][(size_t)(r * 64 + row) * 32 + (q ^ swr) * 8] = av;
        }
    };

    // ---- prologue: issue steps 0 and 1 ----
    issueB(0, 0); issueA(0, 0);
    issueB(1, 1); issueA(1, 1);
    asm volatile("s_waitcnt vmcnt(4)" ::: "memory");   // step0 loads arrived
    writeA(0, 0);
    asm volatile("s_waitcnt lgkmcnt(0)\ns_barrier" ::: "memory");

#pragma unroll
    for (int kc = 0; kc < 8; ++kc) {
        const int p = kc % 3;
        if (kc + 2 < 8) {
            issueB(kc + 2, (kc + 2) % 3);   // 2-ahead prefetch, in flight across barrier
            issueA(kc + 2, (kc + 2) & 1);
        }
        __builtin_amdgcn_sched_barrier(0);   // pin prefetch issue above compute
        bf16x8 af[4], bfr[4];
#pragma unroll
        for (int mi = 0; mi < 4; ++mi)
            af[mi] = *(const bf16x8*)&Alds[p][(wm * 64 + mi * 16 + l15) * 32 + (l4 ^ srd) * 8];
#pragma unroll
        for (int hi = 0; hi < 4; ++hi)
            bfr[hi] = *(const bf16x8*)&Blds[p][(wh * 64 + hi * 16 + l15) * 32 + (l4 ^ srd) * 8];
#pragma unroll
        for (int mi = 0; mi < 4; ++mi)
#pragma unroll
            for (int hi = 0; hi < 4; ++hi)
                acc[mi][hi] = __builtin_amdgcn_mfma_f32_16x16x32_bf16(
                    af[mi], bfr[hi], acc[mi][hi], 0, 0, 0);
        if (kc < 7) {
            if (kc + 2 < 8)
                asm volatile("s_waitcnt vmcnt(4)" ::: "memory");  // kc+1 done, kc+2 in flight
            else
                asm volatile("s_waitcnt vmcnt(0)" ::: "memory");  // tail: drain last loads
            writeA((kc + 1) % 3, (kc + 1) & 1);
            asm volatile("s_waitcnt lgkmcnt(0)\ns_barrier" ::: "memory");
        }
    }

    bf16* Cb = C + (size_t)branch * ((size_t)TCl * 256 * 1024);
#pragma unroll
    for (int mi = 0; mi < 4; ++mi)
#pragma unroll
        for (int hi = 0; hi < 4; ++hi) {
            int rr = m0 + wm * 64 + mi * 16 + l4 * 4;
            int col = h0 + wh * 64 + hi * 16 + l15;
#pragma unroll
            for (int r = 0; r < 4; ++r)
                Cb[(size_t)(rr + r) * 1024 + col] = (bf16)acc[mi][hi][r];
        }
}

// --------------------- P2: dendritic scan + LIF1 (bit-pack s1) -------------
// one thread per (n,h); TCC=0 -> runtime trip count (no prefetch pipelining)
template<int TCC>
__global__ void scan_kernel(const bf16* __restrict__ bin,
                            const float* __restrict__ alf,
                            const float* __restrict__ omf,
                            const float* __restrict__ bbf,
                            const float* __restrict__ b2s,
                            unsigned long long* __restrict__ s1p,
                            float* __restrict__ stw,
                            float* __restrict__ v1w,
                            int t0, int TCl_rt) {
    const int TCl = TCC ? TCC : TCl_rt;
    int n = blockIdx.x >> 2;
    int h = (blockIdx.x & 3) * 256 + threadIdx.x;
    int lane = threadIdx.x & 63;
    int widx = (blockIdx.x & 3) * 4 + (threadIdx.x >> 6);
    size_t CHEc = (size_t)TCl * 256 * 1024;
    size_t base = (size_t)n * 1024 + h;

    float al[NBR], om[NBR], bbv[NBR], st[NBR];
    float v1;
#pragma unroll
    for (int b = 0; b < NBR; ++b) {
        al[b] = alf[b * Hh + h];
        om[b] = omf[b * Hh + h];
        bbv[b] = bbf[b * Hh + h];
    }
    if (t0 == 0) {
#pragma unroll
        for (int b = 0; b < NBR; ++b) st[b] = 0.f;
        v1 = 0.f;
    } else {
#pragma unroll
        for (int b = 0; b < NBR; ++b)
            st[b] = stw[((size_t)b * Nn + n) * Hh + h];
        v1 = v1w[(size_t)n * Hh + h];
    }
    float tau1 = b2s[48];

    float nxt[NBR];
#pragma unroll
    for (int b = 0; b < NBR; ++b) nxt[b] = (float)bin[b * CHEc + base];

#pragma unroll 2
    for (int tl = 0; tl < TCl; ++tl) {
        float cur[NBR];
#pragma unroll
        for (int b = 0; b < NBR; ++b) cur[b] = nxt[b];
        if (tl + 1 < TCl) {
            size_t nb = base + (size_t)(tl + 1) * (256 * 1024);
#pragma unroll
            for (int b = 0; b < NBR; ++b) nxt[b] = (float)bin[b * CHEc + nb];
        }
#pragma unroll
        for (int b = 0; b < NBR; ++b)
            st[b] = al[b] * st[b] + om[b] * (cur[b] + bbv[b]);
        float comb = st[0] + st[1] + st[2] + st[3];
        v1 += (comb - v1) / tau1;
        bool sp = (v1 >= 1.0f);
        unsigned long long m = __ballot(sp);
        if (lane == 0)
            s1p[((size_t)(t0 + tl) * Nn + n) * 16 + widx] = m;
        if (sp) v1 = 0.f;
    }
#pragma unroll
    for (int b = 0; b < NBR; ++b) stw[((size_t)b * Nn + n) * Hh + h] = st[b];
    v1w[(size_t)n * Hh + h] = v1;
}

// --------------------------- GEMM2: s1 @ W2 --------------------------------
__global__ __launch_bounds__(256, 2)
void gemm2_kernel(const unsigned char* __restrict__ s1b,
                  const bf16* __restrict__ W2T, float* __restrict__ h2) {
    __shared__ bf16 Alds[4096];
    __shared__ bf16 Blds[1536];
    int tid = threadIdx.x;
    int m0 = blockIdx.x * 128;
    int w = tid >> 6, lane = tid & 63;
    int l15 = lane & 15, l4 = lane >> 4;

    f32x4 zero = {0.f, 0.f, 0.f, 0.f};
    f32x4 acc[2][3];
#pragma unroll
    for (int mi = 0; mi < 2; ++mi)
#pragma unroll
        for (int hi = 0; hi < 3; ++hi) acc[mi][hi] = zero;

    const bf16 ONE = (bf16)1.0f, ZER = (bf16)0.0f;

    for (int kc = 0; kc < 32; ++kc) {
        bf16x8 av[2], bv;
#pragma unroll
        for (int r = 0; r < 2; ++r) {
            int L = r * 256 + tid;
            int row = L >> 2;
            unsigned char bits = s1b[(size_t)(m0 + row) * 128 + kc * 4 + (L & 3)];
#pragma unroll
            for (int j = 0; j < 8; ++j)
                av[r][j] = ((bits >> j) & 1) ? ONE : ZER;
        }
        if (tid < 192)
            bv = *(const bf16x8*)&W2T[(size_t)(tid >> 2) * 1024 + kc * 32 + (tid & 3) * 8];
        __syncthreads();
#pragma unroll
        for (int r = 0; r < 2; ++r)
            *(bf16x8*)&Alds[(size_t)(r * 256 + tid) * 8] = av[r];
        if (tid < 192)
            *(bf16x8*)&Blds[(size_t)tid * 8] = bv;
        __syncthreads();
        bf16x8 af[2], bfr[3];
#pragma unroll
        for (int mi = 0; mi < 2; ++mi)
            af[mi] = *(const bf16x8*)&Alds[(w * 32 + mi * 16 + l15) * 32 + l4 * 8];
#pragma unroll
        for (int hi = 0; hi < 3; ++hi)
            bfr[hi] = *(const bf16x8*)&Blds[(hi * 16 + l15) * 32 + l4 * 8];
#pragma unroll
        for (int mi = 0; mi < 2; ++mi)
#pragma unroll
            for (int hi = 0; hi < 3; ++hi)
                acc[mi][hi] = __builtin_amdgcn_mfma_f32_16x16x32_bf16(
                    af[mi], bfr[hi], acc[mi][hi], 0, 0, 0);
        __syncthreads();
    }
#pragma unroll
    for (int mi = 0; mi < 2; ++mi)
#pragma unroll
        for (int hi = 0; hi < 3; ++hi) {
            int col = hi * 16 + l15;
#pragma unroll
            for (int r = 0; r < 4; ++r) {
                int m = m0 + w * 32 + mi * 16 + l4 * 4 + r;
                int t = m >> 8;
                int n = m & 255;
                h2[((size_t)n * Tt + t) * 48 + col] = acc[mi][hi][r];
            }
        }
}

// ------------------- P4: LIF2 scan + count + log_softmax (fp32 out) --------
__global__ void out_kernel(const float* __restrict__ h2,
                           const float* __restrict__ b2s,
                           float* __restrict__ out) {
    int n = blockIdx.x;
    int k = threadIdx.x;
    float b2v = (k < 48) ? b2s[k] : 0.f;
    float tau2 = b2s[49];
    float v2 = 0.f, acc = 0.f;
    const float* base = h2 + (size_t)n * Tt * 48;
    for (int t = 0; t < Tt; ++t) {
        float hv = (k < 48) ? base[t * 48 + k] : 0.f;
        hv += b2v;
        v2 += (hv - v2) / tau2;
        bool sp = (v2 >= 1.0f);
        if (sp) { acc += 1.f; v2 = 0.f; }
    }
    float val = (k < OUTK) ? acc : -3.0e38f;
    float mx = val;
#pragma unroll
    for (int o = 32; o > 0; o >>= 1) mx = fmaxf(mx, __shfl_xor(mx, o));
    float e = (k < OUTK) ? expf(val - mx) : 0.f;
    float s = e;
#pragma unroll
    for (int o = 32; o > 0; o >>= 1) s += __shfl_xor(s, o);
    if (k < OUTK) out[n * OUTK + k] = (val - mx) - logf(s);
}

// ---------------------------------------------------------------------------
extern "C" void kernel_launch(void* const* d_in, const int* in_sizes, int n_in,
                              void* d_out, int out_size, void* d_ws, size_t ws_size,
                              hipStream_t stream) {
    const void* x    = d_in[0];
    const void* Wb   = d_in[1];
    const void* bb   = d_in[2];
    const void* taus = d_in[3];
    const void* W2   = d_in[4];
    const void* b2   = d_in[5];
    const void* tau1 = d_in[6];
    const void* tau2 = d_in[7];
    float* out = (float*)d_out;

    char* ws = (char*)d_ws;
    int*   flag = (int*)(ws + OFF_FLAG);
    bf16*  WbT  = (bf16*)(ws + OFF_WBT);
    bf16*  W2T  = (bf16*)(ws + OFF_W2T);
    float* alf  = (float*)(ws + OFF_ALF);
    float* omf  = (float*)(ws + OFF_OMF);
    float* bbf  = (float*)(ws + OFF_BBF);
    float* b2s  = (float*)(ws + OFF_B2S);
    float* h2   = (float*)(ws + OFF_H2);
    float* stw  = (float*)(ws + OFF_STW);
    float* v1w  = (float*)(ws + OFF_V1W);
    unsigned long long* s1p = (unsigned long long*)(ws + OFF_S1P);
    bf16*  bin  = (bf16*)(ws + OFF_BIN);

    // largest t-chunk that fits (bin is bf16: TC * 2,097,152 bytes)
    const int cands[8] = {250, 125, 50, 25, 10, 5, 2, 1};
    int TC = 1;
    for (int i = 0; i < 8; ++i) {
        size_t need = (size_t)FIXED_WS + (size_t)cands[i] * 2097152u;
        if (need <= ws_size) { TC = cands[i]; break; }
    }

    sniff_kernel<<<1, 64, 0, stream>>>((const unsigned short*)x, flag);
    trans_wb_kernel<<<1024, 256, 0, stream>>>(Wb, WbT, flag);
    trans_w2_kernel<<<192, 256, 0, stream>>>(W2, W2T, flag);
    prep_kernel<<<17, 256, 0, stream>>>(taus, bb, b2, tau1, tau2,
                                        alf, omf, bbf, b2s, flag);

    int nch = Tt / TC;
    for (int c = 0; c < nch; ++c) {
        const void* xc = (const void*)((const char*)x +
            (size_t)c * TC * 256 * 1024 * 4);   // fp32 chunk offset (bf16 path
                                                // only triggers when TC==250)
        gemm1_kernel<<<64 * TC, 256, 0, stream>>>(xc, WbT, bin, flag, TC);
        if (TC == 250)
            scan_kernel<250><<<1024, 256, 0, stream>>>(
                bin, alf, omf, bbf, b2s, s1p, stw, v1w, c * TC, TC);
        else
            scan_kernel<0><<<1024, 256, 0, stream>>>(
                bin, alf, omf, bbf, b2s, s1p, stw, v1w, c * TC, TC);
    }
    gemm2_kernel<<<500, 256, 0, stream>>>((const unsigned char*)s1p, W2T, h2);
    out_kernel<<<Nn, 64, 0, stream>>>(h2, b2s, out);

    (void)in_sizes; (void)n_in; (void)out_size;
}